// Round 2
// baseline (433.361 us; speedup 1.0000x reference)
//
#include <hip/hip_runtime.h>

// MultiStepLIF, decay_input=False, hard reset to 0, tau=2, thresh=1.
// x: [T=4, B*N] fp32. out: spikes same shape, fp32 (0.0 or 1.0).
// Per neuron: v = 0.5*v + x_t ; s = (v >= 1) ; v = s ? 0 : v.
//
// One-touch stream (512 MiB total): HBM-bound, floor ~85 us @ 6.3 TB/s.
// Fully unrolled 4 grid-stride chunks with compile-time offsets: 16
// independent nontemporal loads (256 B/lane) issued before any
// compute/store (max per-wave MLP), then compute+stores drain per chunk.
// Exact-fit launch (4096 x 256, 4 chunks/thread) -> no tail.

#define T_STEPS 4

typedef float vf4 __attribute__((ext_vector_type(4)));

__device__ __forceinline__ vf4 lif_step(vf4& v, const vf4 xt)
{
    v = 0.5f * v + xt;
    vf4 s;
    s.x = (v.x >= 1.0f) ? 1.0f : 0.0f;
    s.y = (v.y >= 1.0f) ? 1.0f : 0.0f;
    s.z = (v.z >= 1.0f) ? 1.0f : 0.0f;
    s.w = (v.w >= 1.0f) ? 1.0f : 0.0f;
    v.x = (v.x >= 1.0f) ? 0.0f : v.x;
    v.y = (v.y >= 1.0f) ? 0.0f : v.y;
    v.z = (v.z >= 1.0f) ? 0.0f : v.z;
    v.w = (v.w >= 1.0f) ? 0.0f : v.w;
    return s;
}

__global__ __launch_bounds__(256) void lif_spike_kernel(
    const vf4* __restrict__ x, vf4* __restrict__ out, unsigned n4)
{
    const unsigned S   = gridDim.x * blockDim.x;        // chunk stride
    const unsigned tid = blockIdx.x * blockDim.x + threadIdx.x;

    if (tid + 3u * S < n4) {
        // Fast path: exactly 4 chunks per thread (host guarantees exact fit).
        // Stage all 16 loads first — 4 chunks x 4 time-planes, every offset
        // compile-time static so xv[][] lives in registers.
        vf4 xv[4][T_STEPS];
#pragma unroll
        for (int k = 0; k < 4; ++k) {
            const unsigned i = tid + (unsigned)k * S;
#pragma unroll
            for (int t = 0; t < T_STEPS; ++t)
                xv[k][t] = __builtin_nontemporal_load(&x[(size_t)t * n4 + i]);
        }
#pragma unroll
        for (int k = 0; k < 4; ++k) {
            const unsigned i = tid + (unsigned)k * S;
            vf4 v = (vf4)(0.f);
#pragma unroll
            for (int t = 0; t < T_STEPS; ++t) {
                const vf4 s = lif_step(v, xv[k][t]);
                __builtin_nontemporal_store(s, &out[(size_t)t * n4 + i]);
            }
        }
    } else {
        // Generic tail path (not taken with the exact-fit launch below).
        for (unsigned i = tid; i < n4; i += S) {
            const vf4 x0 = __builtin_nontemporal_load(&x[(size_t)0 * n4 + i]);
            const vf4 x1 = __builtin_nontemporal_load(&x[(size_t)1 * n4 + i]);
            const vf4 x2 = __builtin_nontemporal_load(&x[(size_t)2 * n4 + i]);
            const vf4 x3 = __builtin_nontemporal_load(&x[(size_t)3 * n4 + i]);
            vf4 v = (vf4)(0.f);
            const vf4 s0 = lif_step(v, x0);
            const vf4 s1 = lif_step(v, x1);
            const vf4 s2 = lif_step(v, x2);
            const vf4 s3 = lif_step(v, x3);
            __builtin_nontemporal_store(s0, &out[(size_t)0 * n4 + i]);
            __builtin_nontemporal_store(s1, &out[(size_t)1 * n4 + i]);
            __builtin_nontemporal_store(s2, &out[(size_t)2 * n4 + i]);
            __builtin_nontemporal_store(s3, &out[(size_t)3 * n4 + i]);
        }
    }
}

extern "C" void kernel_launch(void* const* d_in, const int* in_sizes, int n_in,
                              void* d_out, int out_size, void* d_ws, size_t ws_size,
                              hipStream_t stream)
{
    const float* x = (const float*)d_in[0];
    float* out = (float*)d_out;

    const int n_total = in_sizes[0];          // T * B * N = 67,108,864
    const unsigned n4 = (unsigned)(n_total / T_STEPS / 4);  // 4,194,304

    const int block = 256;
    // Exact fit: 4 chunks/thread. n4 = 4,194,304 -> grid = 4096 (16 WG/CU).
    int grid = (int)(n4 / (unsigned)(block * 4));
    if (grid < 1) grid = 1;
    if ((unsigned)grid * (unsigned)block * 4u != n4) {
        // Non-exact shape: fall back to grid-stride coverage.
        grid = (int)((n4 + block - 1) / block);
        if (grid > 4096) grid = 4096;
    }

    lif_spike_kernel<<<grid, block, 0, stream>>>(
        (const vf4*)x, (vf4*)out, n4);
}

// Round 3
// 431.377 us; speedup vs baseline: 1.0046x; 1.0046x over previous
//
#include <hip/hip_runtime.h>

// MultiStepLIF, decay_input=False, hard reset to 0, tau=2, thresh=1.
// x: [T=4, B*N] fp32. out: spikes same shape, fp32 (0.0 or 1.0).
// Per neuron: v = 0.5*v + x_t ; s = (v >= 1) ; v = s ? 0 : v.
//
// One-touch stream (512 MiB total). Rocprof r2: harness re-poison fills
// (2 x 165 us @ 6.5 TB/s) dominate dur_us; kernel portion ~103 us
// (~5.2 TB/s). This version targets the kernel's R/W mix:
//   - NT loads (one-touch reads must not evict pending write lines)
//   - PLAIN stores (let L2 aggregate/drain write-backs — fills hit
//     6.5 TB/s with cached stores; NT stores suspected -20% BW)
//   - rolled m13 copy-pattern loop, low VGPR, __launch_bounds__(256,8)
//     => <=64 VGPR, 32 waves/CU for max TLP.

#define T_STEPS 4

typedef float vf4 __attribute__((ext_vector_type(4)));

__device__ __forceinline__ vf4 lif_step(vf4& v, const vf4 xt)
{
    v = 0.5f * v + xt;
    vf4 s;
    s.x = (v.x >= 1.0f) ? 1.0f : 0.0f;
    s.y = (v.y >= 1.0f) ? 1.0f : 0.0f;
    s.z = (v.z >= 1.0f) ? 1.0f : 0.0f;
    s.w = (v.w >= 1.0f) ? 1.0f : 0.0f;
    v.x = (v.x >= 1.0f) ? 0.0f : v.x;
    v.y = (v.y >= 1.0f) ? 0.0f : v.y;
    v.z = (v.z >= 1.0f) ? 0.0f : v.z;
    v.w = (v.w >= 1.0f) ? 0.0f : v.w;
    return s;
}

__global__ __launch_bounds__(256, 8) void lif_spike_kernel(
    const vf4* __restrict__ x, vf4* __restrict__ out, unsigned n4)
{
    const unsigned stride = gridDim.x * blockDim.x;
    for (unsigned i = blockIdx.x * blockDim.x + threadIdx.x; i < n4; i += stride) {
        // 4 independent NT loads in flight (t-major planes, 64 MiB apart;
        // unit-stride across lanes per instruction).
        const vf4 x0 = __builtin_nontemporal_load(&x[(size_t)0 * n4 + i]);
        const vf4 x1 = __builtin_nontemporal_load(&x[(size_t)1 * n4 + i]);
        const vf4 x2 = __builtin_nontemporal_load(&x[(size_t)2 * n4 + i]);
        const vf4 x3 = __builtin_nontemporal_load(&x[(size_t)3 * n4 + i]);

        vf4 v = (vf4)(0.f);
        const vf4 s0 = lif_step(v, x0);
        const vf4 s1 = lif_step(v, x1);
        const vf4 s2 = lif_step(v, x2);
        const vf4 s3 = lif_step(v, x3);

        // Plain cached stores: full 64B lines, L2 aggregates the write-back.
        out[(size_t)0 * n4 + i] = s0;
        out[(size_t)1 * n4 + i] = s1;
        out[(size_t)2 * n4 + i] = s2;
        out[(size_t)3 * n4 + i] = s3;
    }
}

extern "C" void kernel_launch(void* const* d_in, const int* in_sizes, int n_in,
                              void* d_out, int out_size, void* d_ws, size_t ws_size,
                              hipStream_t stream)
{
    const float* x = (const float*)d_in[0];
    float* out = (float*)d_out;

    const int n_total = in_sizes[0];          // T * B * N = 67,108,864
    const unsigned n4 = (unsigned)(n_total / T_STEPS / 4);  // 4,194,304

    const int block = 256;
    const int grid = 4096;   // 16 WGs/CU; exactly 4 grid-stride iters/thread

    lif_spike_kernel<<<grid, block, 0, stream>>>(
        (const vf4*)x, (vf4*)out, n4);
}